// Round 4
// baseline (206.119 us; speedup 1.0000x reference)
//
#include <hip/hip_runtime.h>
#include <cstdint>

#define LDP 136          // padded LDS row stride in bf16 elems (272B, 16B-aligned)
#define INFV 3.0e38f

typedef short bf16x8 __attribute__((ext_vector_type(8)));
typedef float f32x4  __attribute__((ext_vector_type(4)));

__device__ inline float bf2f(uint32_t bits){
  return __builtin_bit_cast(float, bits << 16);
}
__device__ inline ushort f2bf(float f){
  uint32_t u = __builtin_bit_cast(uint32_t, f);
  u += 0x7fffu + ((u >> 16) & 1u);   // round-to-nearest-even
  return (ushort)(u >> 16);
}

// ---- DPP helpers: VALU cross-lane (no ds_bpermute) ------------------------
#define DPPF(x, oldv, ctrl) \
  __builtin_bit_cast(float, __builtin_amdgcn_update_dpp( \
      __builtin_bit_cast(int,(oldv)), __builtin_bit_cast(int,(x)), \
      (ctrl), 0xf, 0xf, false))

__device__ inline float scan_add16(float x){   // inclusive add-scan within 16-lane row
  x += DPPF(x, 0.0f, 0x111);
  x += DPPF(x, 0.0f, 0x112);
  x += DPPF(x, 0.0f, 0x114);
  x += DPPF(x, 0.0f, 0x118);
  return x;
}
__device__ inline float scan_min16(float x){   // inclusive min-scan within 16-lane row
  x = fminf(x, DPPF(x, INFV, 0x111));
  x = fminf(x, DPPF(x, INFV, 0x112));
  x = fminf(x, DPPF(x, INFV, 0x114));
  x = fminf(x, DPPF(x, INFV, 0x118));
  return x;
}
__device__ inline float rl(float v, int l){    // readlane (uniform, VALU)
  return __builtin_bit_cast(float, __builtin_amdgcn_readlane(__builtin_bit_cast(int, v), l));
}

// ---------------------------------------------------------------------------
// Kernel 1: cost[b][i][j] = ||s1[b,i]||^2 + ||s2[b,j]||^2 - 2*dot  (bf16 out)
// ---------------------------------------------------------------------------
__global__ __launch_bounds__(256) void dtw_cost_gemm(
    const float* __restrict__ s1, const float* __restrict__ s2,
    ushort* __restrict__ cost)
{
  __shared__ ushort As[128*LDP];
  __shared__ ushort Bs[128*LDP];
  __shared__ float  n1s[128];
  __shared__ float  n2s[128];

  const int b  = blockIdx.y;
  const int ti = blockIdx.x / 3;
  const int tj = blockIdx.x % 3;
  const int t  = threadIdx.x;

  // ---- stage A,B tiles fp32 -> bf16 into LDS ----
  {
    const int row = t >> 1;
    const int par = t & 1;
    const float* Arow = s1 + ((size_t)(b*384 + ti*128 + row)) * 128;
    const float* Brow = s2 + ((size_t)(b*384 + tj*128 + row)) * 128;
    ushort* Asr = As + row*LDP;
    ushort* Bsr = Bs + row*LDP;
#pragma unroll
    for (int q = 0; q < 16; q++){
      const int col = ((2*q + par + 15*row) & 31) * 4;
      float4 va = *(const float4*)(Arow + col);
      float4 vb = *(const float4*)(Brow + col);
      ushort4 ua = make_ushort4(f2bf(va.x), f2bf(va.y), f2bf(va.z), f2bf(va.w));
      ushort4 ub = make_ushort4(f2bf(vb.x), f2bf(vb.y), f2bf(vb.z), f2bf(vb.w));
      *(ushort4*)(Asr + col) = ua;
      *(ushort4*)(Bsr + col) = ub;
    }
  }
  __syncthreads();

  // ---- row norms from the bf16 tiles ----
  {
    const ushort* rowp = (t < 128) ? (As + t*LDP) : (Bs + (t-128)*LDP);
    float s = 0.0f;
#pragma unroll
    for (int e = 0; e < 128; e += 8){
      bf16x8 v = *(const bf16x8*)(rowp + e);
#pragma unroll
      for (int k = 0; k < 8; k++){
        float f = bf2f((uint16_t)v[k]);
        s += f*f;
      }
    }
    if (t < 128) n1s[t] = s; else n2s[t-128] = s;
  }
  __syncthreads();

  // ---- MFMA: 4 waves in 2x2, each 64x64 via 4x4 frags of 16x16x32 ----
  const int lane = t & 63;
  const int wid  = t >> 6;
  const int wr = wid >> 1, wc = wid & 1;
  const int lrow = lane & 15;
  const int lk   = lane >> 4;

  f32x4 acc[4][4] = {};
#pragma unroll
  for (int kk = 0; kk < 4; kk++){
    const int kb = kk*32 + lk*8;
    bf16x8 af[4], bfv[4];
#pragma unroll
    for (int f = 0; f < 4; f++){
      af[f]  = *(const bf16x8*)(As + (wr*64 + f*16 + lrow)*LDP + kb);
      bfv[f] = *(const bf16x8*)(Bs + (wc*64 + f*16 + lrow)*LDP + kb);
    }
#pragma unroll
    for (int i = 0; i < 4; i++)
#pragma unroll
      for (int j = 0; j < 4; j++)
        acc[i][j] = __builtin_amdgcn_mfma_f32_16x16x32_bf16(af[i], bfv[j], acc[i][j], 0, 0, 0);
  }

  // ---- epilogue ----
  ushort* Cb = cost + (size_t)b * 147456;  // 384*384
  const int i0 = ti*128 + wr*64;
  const int j0 = tj*128 + wc*64;
  float n2v[4];
#pragma unroll
  for (int fj = 0; fj < 4; fj++) n2v[fj] = n2s[wc*64 + fj*16 + lrow];
#pragma unroll
  for (int fi = 0; fi < 4; fi++){
#pragma unroll
    for (int r = 0; r < 4; r++){
      const int il = wr*64 + fi*16 + lk*4 + r;
      const int i  = i0 + fi*16 + lk*4 + r;
      const float n1v = n1s[il];
#pragma unroll
      for (int fj = 0; fj < 4; fj++){
        float cv = n1v + n2v[fj] - 2.0f*acc[fi][fj][r];
        Cb[(size_t)i*384 + (j0 + fj*16 + lrow)] = f2bf(cv);
      }
    }
  }
}

// ---------------------------------------------------------------------------
// Kernel 2: DTW DP. One wave per batch; 64 lanes x 6 cols = 384.
// min-plus scan row recurrence (DPP + readlane). Cost-row loads are
// asm-volatile global_load_dword into an 8-row register ring with COUNTED
// s_waitcnt vmcnt(N): volatile-asm program order makes the pipeline
// structural — the compiler cannot sink the loads or over-wait.
// ---------------------------------------------------------------------------
__global__ __launch_bounds__(64, 1) void dtw_dp(
    const ushort* __restrict__ cost, float* __restrict__ partial)
{
  const int b    = blockIdx.x;
  const int lane = threadIdx.x;
  const int row  = lane >> 4;           // 16-lane DPP row id (0..3)
  const bool l16z = (lane & 15) == 0;
  const uint32_t* Cw = (const uint32_t*)(cost + (size_t)b * 147456);
  const int wb = lane * 3;   // 3 dwords = 6 bf16 per lane per row (row = 192 dwords)

  float r0,r1,r2,r3,r4,r5;

  // issue 3 dword loads for one row into 3 named regs; volatile => ordered
#define ISSUE3(d0, d1, d2, ptr) \
  asm volatile("global_load_dword %0, %3, off\n\t" \
               "global_load_dword %1, %3, off offset:4\n\t" \
               "global_load_dword %2, %3, off offset:8" \
               : "=&v"(d0), "=&v"(d1), "=&v"(d2) : "v"(ptr))

#define WAIT_SB(n) do { \
    asm volatile("s_waitcnt vmcnt(" #n ")" ::: "memory"); \
    __builtin_amdgcn_sched_barrier(0); \
  } while(0)

#define ROW_BODY(W0, W1, W2) do { \
    float c0=bf2f((W0)&0xffffu), c1=bf2f((W0)>>16), \
          c2=bf2f((W1)&0xffffu), c3=bf2f((W1)>>16), \
          c4=bf2f((W2)&0xffffu), c5=bf2f((W2)>>16); \
    /* prev-row r5 shifted right by one lane */ \
    float yv = DPPF(r5, INFV, 0x111); \
    float q0 = rl(r5,15), q1 = rl(r5,31), q2 = rl(r5,47); \
    float fix = (lane==16)? q0 : (lane==32)? q1 : q2; \
    float pm0 = l16z ? ((lane==0)? INFV : fix) : yv; \
    float a0 = c0 + fminf(r0, pm0); \
    float a1 = c1 + fminf(r1, r0); \
    float a2 = c2 + fminf(r2, r1); \
    float a3 = c3 + fminf(r3, r2); \
    float a4 = c4 + fminf(r4, r3); \
    float a5 = c5 + fminf(r5, r4); \
    /* S = inclusive prefix sum of c across 384 */ \
    float s0=c0, s1=s0+c1, s2=s1+c2, s3=s2+c3, s4=s3+c4, s5=s4+c5; \
    float incl = scan_add16(s5); \
    float exl  = DPPF(incl, 0.0f, 0x111); \
    float t0 = rl(incl,15), t1 = rl(incl,31), t2 = rl(incl,47); \
    float rowoff = (row==0)? 0.0f : (row==1)? t0 : (row==2)? (t0+t1) : (t0+t1+t2); \
    float excl = exl + rowoff; \
    s0+=excl; s1+=excl; s2+=excl; s3+=excl; s4+=excl; s5+=excl; \
    /* prefix-min of (a - S); row = min(m, e) + S */ \
    float m0 = a0-s0; \
    float m1 = fminf(m0, a1-s1); \
    float m2 = fminf(m1, a2-s2); \
    float m3 = fminf(m2, a3-s3); \
    float m4 = fminf(m3, a4-s4); \
    float m5v = fminf(m4, a5-s5); \
    float im = scan_min16(m5v); \
    float ym = DPPF(im, INFV, 0x111); \
    float u0 = rl(im,15), u1 = rl(im,31), u2 = rl(im,47); \
    float moff = (row==0)? INFV : (row==1)? u0 : (row==2)? fminf(u0,u1) : fminf(u0,fminf(u1,u2)); \
    float e = fminf(ym, moff); \
    r0 = fminf(m0,e)+s0; \
    r1 = fminf(m1,e)+s1; \
    r2 = fminf(m2,e)+s2; \
    r3 = fminf(m3,e)+s3; \
    r4 = fminf(m4,e)+s4; \
    r5 = fminf(m5v,e)+s5; \
  } while(0)

  uint32_t ring[8][3];
  uint32_t z0, z1, z2;

  // prologue: row 0 first (oldest in queue), then rows 1..8 -> 27 outstanding
  ISSUE3(z0, z1, z2, Cw + wb);
#pragma unroll
  for (int u = 0; u < 8; u++)
    ISSUE3(ring[u][0], ring[u][1], ring[u][2], Cw + (size_t)(1+u)*192 + wb);

  WAIT_SB(24);   // row 0 ready, rows 1..8 still in flight

  // ---- row 0: inclusive prefix sum of cost row 0 ----
  {
    float c0=bf2f(z0&0xffffu), c1=bf2f(z0>>16),
          c2=bf2f(z1&0xffffu), c3=bf2f(z1>>16),
          c4=bf2f(z2&0xffffu), c5=bf2f(z2>>16);
    float s0=c0, s1=s0+c1, s2=s1+c2, s3=s2+c3, s4=s3+c4, s5=s4+c5;
    float incl = scan_add16(s5);
    float exl  = DPPF(incl, 0.0f, 0x111);
    float t0 = rl(incl,15), t1 = rl(incl,31), t2 = rl(incl,47);
    float rowoff = (row==0)? 0.0f : (row==1)? t0 : (row==2)? (t0+t1) : (t0+t1+t2);
    float excl = exl + rowoff;
    r0=s0+excl; r1=s1+excl; r2=s2+excl; r3=s3+excl; r4=s4+excl; r5=s5+excl;
  }

  // ---- main: 47 groups x 8 rows = rows 1..376; steady state 24 outstanding
  for (int k = 0; k < 47; ++k){
    const int base = 8*k;
#pragma unroll
    for (int u = 0; u < 8; u++){
      WAIT_SB(21);                       // oldest 3 (this row) complete
      uint32_t w0 = ring[u][0], w1 = ring[u][1], w2 = ring[u][2];
      int pr = base + u + 9;             // prefetch 8 rows ahead
      if (pr > 383) pr = 383;            // clamped dummy keeps counts uniform
      ISSUE3(ring[u][0], ring[u][1], ring[u][2], Cw + (size_t)pr*192 + wb);
      ROW_BODY(w0, w1, w2);
    }
  }

  // ---- tail: rows 377..383 in slots 0..6 (slot 7 = dup of 383, unused)
#define TAIL(u, n) do { \
    WAIT_SB(n); \
    uint32_t w0 = ring[u][0], w1 = ring[u][1], w2 = ring[u][2]; \
    ROW_BODY(w0, w1, w2); \
  } while(0)
  TAIL(0, 21); TAIL(1, 18); TAIL(2, 15); TAIL(3, 12);
  TAIL(4, 9);  TAIL(5, 6);  TAIL(6, 3);
  asm volatile("s_waitcnt vmcnt(0)" ::: "memory");

  if (lane == 63) partial[b] = r5;
}

// ---------------------------------------------------------------------------
// Kernel 3: mean of 128 partials -> out[0]
// ---------------------------------------------------------------------------
__global__ __launch_bounds__(64) void dtw_reduce(
    const float* __restrict__ partial, float* __restrict__ out)
{
  const int l = threadIdx.x;
  float v = partial[l] + partial[l + 64];
#pragma unroll
  for (int d = 32; d >= 1; d >>= 1) v += __shfl_xor(v, d, 64);
  if (l == 0) out[0] = v * (1.0f/128.0f);
}

extern "C" void kernel_launch(void* const* d_in, const int* in_sizes, int n_in,
                              void* d_out, int out_size, void* d_ws, size_t ws_size,
                              hipStream_t stream)
{
  (void)in_sizes; (void)n_in; (void)out_size; (void)ws_size;
  const float* s1 = (const float*)d_in[0];
  const float* s2 = (const float*)d_in[1];
  float* out = (float*)d_out;

  ushort* cost    = (ushort*)d_ws;                                   // 128*384*384*2 B
  float*  partial = (float*)((char*)d_ws + (size_t)128*147456*2);    // 128 floats

  dtw_cost_gemm<<<dim3(9, 128), dim3(256), 0, stream>>>(s1, s2, cost);
  dtw_dp<<<dim3(128), dim3(64), 0, stream>>>(cost, partial);
  dtw_reduce<<<dim3(1), dim3(64), 0, stream>>>(partial, out);
}

// Round 5
// 129.516 us; speedup vs baseline: 1.5915x; 1.5915x over previous
//
#include <hip/hip_runtime.h>
#include <cstdint>

#define LDP 136          // padded LDS row stride in bf16 elems (272B, 16B-aligned)
#define INFV 3.0e38f

typedef short bf16x8 __attribute__((ext_vector_type(8)));
typedef float f32x4  __attribute__((ext_vector_type(4)));

__device__ inline float bf2f(uint32_t bits){
  return __builtin_bit_cast(float, bits << 16);
}
__device__ inline float bf2f_lo(uint32_t w){ return __builtin_bit_cast(float, w << 16); }
__device__ inline float bf2f_hi(uint32_t w){ return __builtin_bit_cast(float, w & 0xffff0000u); }
__device__ inline ushort f2bf(float f){
  uint32_t u = __builtin_bit_cast(uint32_t, f);
  u += 0x7fffu + ((u >> 16) & 1u);   // round-to-nearest-even
  return (ushort)(u >> 16);
}

// ---- DPP helpers: VALU cross-lane ----------------------------------------
#define DPPF(x, oldv, ctrl) \
  __builtin_bit_cast(float, __builtin_amdgcn_update_dpp( \
      __builtin_bit_cast(int,(oldv)), __builtin_bit_cast(int,(x)), \
      (ctrl), 0xf, 0xf, false))

__device__ inline float scan_add16(float x){   // inclusive add-scan within 16-lane row
  x += DPPF(x, 0.0f, 0x111);
  x += DPPF(x, 0.0f, 0x112);
  x += DPPF(x, 0.0f, 0x114);
  x += DPPF(x, 0.0f, 0x118);
  return x;
}
__device__ inline float scan_min16(float x){   // inclusive min-scan within 16-lane row
  x = fminf(x, DPPF(x, INFV, 0x111));
  x = fminf(x, DPPF(x, INFV, 0x112));
  x = fminf(x, DPPF(x, INFV, 0x114));
  x = fminf(x, DPPF(x, INFV, 0x118));
  return x;
}
__device__ inline float rl(float v, int l){    // readlane (uniform, VALU)
  return __builtin_bit_cast(float, __builtin_amdgcn_readlane(__builtin_bit_cast(int, v), l));
}

// ---------------------------------------------------------------------------
// Kernel 1: cost[b][i][j] = ||s1[b,i]||^2 + ||s2[b,j]||^2 - 2*dot  (bf16 out)
// ---------------------------------------------------------------------------
__global__ __launch_bounds__(256) void dtw_cost_gemm(
    const float* __restrict__ s1, const float* __restrict__ s2,
    ushort* __restrict__ cost)
{
  __shared__ ushort As[128*LDP];
  __shared__ ushort Bs[128*LDP];
  __shared__ float  n1s[128];
  __shared__ float  n2s[128];

  const int b  = blockIdx.y;
  const int ti = blockIdx.x / 3;
  const int tj = blockIdx.x % 3;
  const int t  = threadIdx.x;

  {
    const int row = t >> 1;
    const int par = t & 1;
    const float* Arow = s1 + ((size_t)(b*384 + ti*128 + row)) * 128;
    const float* Brow = s2 + ((size_t)(b*384 + tj*128 + row)) * 128;
    ushort* Asr = As + row*LDP;
    ushort* Bsr = Bs + row*LDP;
#pragma unroll
    for (int q = 0; q < 16; q++){
      const int col = ((2*q + par + 15*row) & 31) * 4;
      float4 va = *(const float4*)(Arow + col);
      float4 vb = *(const float4*)(Brow + col);
      ushort4 ua = make_ushort4(f2bf(va.x), f2bf(va.y), f2bf(va.z), f2bf(va.w));
      ushort4 ub = make_ushort4(f2bf(vb.x), f2bf(vb.y), f2bf(vb.z), f2bf(vb.w));
      *(ushort4*)(Asr + col) = ua;
      *(ushort4*)(Bsr + col) = ub;
    }
  }
  __syncthreads();

  {
    const ushort* rowp = (t < 128) ? (As + t*LDP) : (Bs + (t-128)*LDP);
    float s = 0.0f;
#pragma unroll
    for (int e = 0; e < 128; e += 8){
      bf16x8 v = *(const bf16x8*)(rowp + e);
#pragma unroll
      for (int k = 0; k < 8; k++){
        float f = bf2f((uint16_t)v[k]);
        s += f*f;
      }
    }
    if (t < 128) n1s[t] = s; else n2s[t-128] = s;
  }
  __syncthreads();

  const int lane = t & 63;
  const int wid  = t >> 6;
  const int wr = wid >> 1, wc = wid & 1;
  const int lrow = lane & 15;
  const int lk   = lane >> 4;

  f32x4 acc[4][4] = {};
#pragma unroll
  for (int kk = 0; kk < 4; kk++){
    const int kb = kk*32 + lk*8;
    bf16x8 af[4], bfv[4];
#pragma unroll
    for (int f = 0; f < 4; f++){
      af[f]  = *(const bf16x8*)(As + (wr*64 + f*16 + lrow)*LDP + kb);
      bfv[f] = *(const bf16x8*)(Bs + (wc*64 + f*16 + lrow)*LDP + kb);
    }
#pragma unroll
    for (int i = 0; i < 4; i++)
#pragma unroll
      for (int j = 0; j < 4; j++)
        acc[i][j] = __builtin_amdgcn_mfma_f32_16x16x32_bf16(af[i], bfv[j], acc[i][j], 0, 0, 0);
  }

  ushort* Cb = cost + (size_t)b * 147456;  // 384*384
  const int i0 = ti*128 + wr*64;
  const int j0 = tj*128 + wc*64;
  float n2v[4];
#pragma unroll
  for (int fj = 0; fj < 4; fj++) n2v[fj] = n2s[wc*64 + fj*16 + lrow];
#pragma unroll
  for (int fi = 0; fi < 4; fi++){
#pragma unroll
    for (int r = 0; r < 4; r++){
      const int il = wr*64 + fi*16 + lk*4 + r;
      const int i  = i0 + fi*16 + lk*4 + r;
      const float n1v = n1s[il];
#pragma unroll
      for (int fj = 0; fj < 4; fj++){
        float cv = n1v + n2v[fj] - 2.0f*acc[fi][fj][r];
        Cb[(size_t)i*384 + (j0 + fj*16 + lrow)] = f2bf(cv);
      }
    }
  }
}

// ---------------------------------------------------------------------------
// Kernel 2: DTW DP, software-pipelined: Stage A (row-local prefix sums,
// independent of DP state) for row i+1 is computed in the same scheduling
// region as Stage B (the serial min-plus recurrence) for row i, so the
// in-order wave fills B's dependency stalls with A's instructions.
// ---------------------------------------------------------------------------
__global__ __launch_bounds__(64, 1) void dtw_dp(
    const ushort* __restrict__ cost, float* __restrict__ partial)
{
  const int b    = blockIdx.x;
  const int lane = threadIdx.x;
  const int row  = lane >> 4;           // 16-lane DPP row id (0..3)
  const uint32_t* Cw = (const uint32_t*)(cost + (size_t)b * 147456);
  const int wb = lane * 3;   // 3 dwords = 6 bf16 per lane per row (row = 192 dwords)

  float r0,r1,r2,r3,r4,r5;                       // DP state (prev row)
  float sp0,sp1,sp2,sp3,sp4,sp5;                 // S[j] for pending row
  float dq0,dq1,dq2,dq3,dq4,dq5;                 // c[j]-S[j] for pending row
  uint32_t ring[4][3];

#define LOADROW(sl, ri) do { \
    int rr_ = (ri); rr_ = rr_ > 383 ? 383 : rr_; \
    const uint32_t* p_ = Cw + (size_t)rr_*192 + wb; \
    ring[sl][0]=p_[0]; ring[sl][1]=p_[1]; ring[sl][2]=p_[2]; \
  } while(0)

  // Stage A: S (global inclusive prefix sum of row costs) and D = c - S.
#define STAGE_A(W0,W1,W2, S0,S1,S2,S3,S4,S5, D0,D1,D2,D3,D4,D5) do { \
    float c0=bf2f_lo(W0), c1=bf2f_hi(W0), c2=bf2f_lo(W1), \
          c3=bf2f_hi(W1), c4=bf2f_lo(W2), c5=bf2f_hi(W2); \
    float t0_=c0, t1_=t0_+c1, t2_=t1_+c2, t3_=t2_+c3, t4_=t3_+c4, t5_=t4_+c5; \
    float incl = scan_add16(t5_); \
    float exl  = DPPF(incl, 0.0f, 0x111); \
    float ta=rl(incl,15), tb=rl(incl,31), tc=rl(incl,47); \
    float g1 = (row>=1)? ta : 0.0f; \
    float g2 = (row>=2)? tb : 0.0f; \
    float g3 = (row>=3)? tc : 0.0f; \
    float excl = exl + ((g1+g2)+g3); \
    S0=t0_+excl; S1=t1_+excl; S2=t2_+excl; S3=t3_+excl; S4=t4_+excl; S5=t5_+excl; \
    D0=c0-S0; D1=c1-S1; D2=c2-S2; D3=c3-S3; D4=c4-S4; D5=c5-S5; \
  } while(0)

  // Stage B: x_j = D_j + min(r_j, r_{j-1}); prefix-min (Sklansky d=3);
  // 16-scan + boundary min; r_j = min(p_j, e) + S_j.
#define STAGE_B(S0,S1,S2,S3,S4,S5, D0,D1,D2,D3,D4,D5) do { \
    float yv = DPPF(r5, INFV, 0x111); \
    float q0=rl(r5,15), q1=rl(r5,31), q2=rl(r5,47); \
    float f1 = (lane==16)? q0 : INFV; \
    float f2 = (lane==32)? q1 : INFV; \
    float f3 = (lane==48)? q2 : INFV; \
    float pm0 = fminf(fminf(f1,f2), fminf(f3,yv)); \
    float x0 = D0 + fminf(r0, pm0); \
    float x1 = D1 + fminf(r1, r0); \
    float x2 = D2 + fminf(r2, r1); \
    float x3 = D3 + fminf(r3, r2); \
    float x4 = D4 + fminf(r4, r3); \
    float x5 = D5 + fminf(r5, r4); \
    float y1 = fminf(x0,x1), y3 = fminf(x2,x3), y5 = fminf(x4,x5); \
    float p2 = fminf(y1,x2), p3 = fminf(y1,y3); \
    float p4 = fminf(p3,x4), p5 = fminf(p3,y5); \
    float im = scan_min16(p5); \
    float ym = DPPF(im, INFV, 0x111); \
    float u0=rl(im,15), u1=rl(im,31), u2=rl(im,47); \
    float h1=(row>=1)?u0:INFV, h2=(row>=2)?u1:INFV, h3=(row>=3)?u2:INFV; \
    float e = fminf(fminf(h1,h2), fminf(h3,ym)); \
    r0 = fminf(x0,e)+S0; \
    r1 = fminf(y1,e)+S1; \
    r2 = fminf(p2,e)+S2; \
    r3 = fminf(p3,e)+S3; \
    r4 = fminf(p4,e)+S4; \
    r5 = fminf(p5,e)+S5; \
  } while(0)

  // body(i): read row i+1 from slot, start load of row i+5 into same slot,
  // Stage A(i+1) into fresh regs, Stage B(i) on pending regs, rotate.
#define BODY(i, sl) do { \
    uint32_t a0=ring[sl][0], a1=ring[sl][1], a2=ring[sl][2]; \
    LOADROW(sl, (i)+5); \
    float sn0,sn1,sn2,sn3,sn4,sn5, dn0,dn1,dn2,dn3,dn4,dn5; \
    STAGE_A(a0,a1,a2, sn0,sn1,sn2,sn3,sn4,sn5, dn0,dn1,dn2,dn3,dn4,dn5); \
    STAGE_B(sp0,sp1,sp2,sp3,sp4,sp5, dq0,dq1,dq2,dq3,dq4,dq5); \
    sp0=sn0; sp1=sn1; sp2=sn2; sp3=sn3; sp4=sn4; sp5=sn5; \
    dq0=dn0; dq1=dn1; dq2=dn2; dq3=dn3; dq4=dn4; dq5=dn5; \
  } while(0)

  // ---- prologue: rows 0..3 in ring; row0 -> r; row1 -> sp/dq ----
  LOADROW(0,0); LOADROW(1,1); LOADROW(2,2); LOADROW(3,3);
  {
    uint32_t a0=ring[0][0], a1=ring[0][1], a2=ring[0][2];
    STAGE_A(a0,a1,a2, sp0,sp1,sp2,sp3,sp4,sp5, dq0,dq1,dq2,dq3,dq4,dq5);
    r0=sp0; r1=sp1; r2=sp2; r3=sp3; r4=sp4; r5=sp5;   // DTW row 0 = prefix sums
  }
  {
    uint32_t a0=ring[1][0], a1=ring[1][1], a2=ring[1][2];
    STAGE_A(a0,a1,a2, sp0,sp1,sp2,sp3,sp4,sp5, dq0,dq1,dq2,dq3,dq4,dq5);
  }
  LOADROW(0,4); LOADROW(1,5);

  // ---- main: k=0..94 covers rows 1..380 (body(i) consumes slot (i+1)&3) ----
  for (int k = 0; k < 95; ++k){
    const int i = 1 + 4*k;
    BODY(i,   2);
    BODY(i+1, 3);
    BODY(i+2, 0);
    BODY(i+3, 1);
  }
  // ---- tail: rows 381..383 ----
  BODY(381, 2);
  BODY(382, 3);
  BODY(383, 0);   // its Stage A output is junk (clamped row), never consumed

  if (lane == 63) partial[b] = r5;
}

// ---------------------------------------------------------------------------
// Kernel 3: mean of 128 partials -> out[0]
// ---------------------------------------------------------------------------
__global__ __launch_bounds__(64) void dtw_reduce(
    const float* __restrict__ partial, float* __restrict__ out)
{
  const int l = threadIdx.x;
  float v = partial[l] + partial[l + 64];
#pragma unroll
  for (int d = 32; d >= 1; d >>= 1) v += __shfl_xor(v, d, 64);
  if (l == 0) out[0] = v * (1.0f/128.0f);
}

extern "C" void kernel_launch(void* const* d_in, const int* in_sizes, int n_in,
                              void* d_out, int out_size, void* d_ws, size_t ws_size,
                              hipStream_t stream)
{
  (void)in_sizes; (void)n_in; (void)out_size; (void)ws_size;
  const float* s1 = (const float*)d_in[0];
  const float* s2 = (const float*)d_in[1];
  float* out = (float*)d_out;

  ushort* cost    = (ushort*)d_ws;                                   // 128*384*384*2 B
  float*  partial = (float*)((char*)d_ws + (size_t)128*147456*2);    // 128 floats

  dtw_cost_gemm<<<dim3(9, 128), dim3(256), 0, stream>>>(s1, s2, cost);
  dtw_dp<<<dim3(128), dim3(64), 0, stream>>>(cost, partial);
  dtw_reduce<<<dim3(1), dim3(64), 0, stream>>>(partial, out);
}